// Round 12
// baseline (294.282 us; speedup 1.0000x reference)
//
#include <hip/hip_runtime.h>
#include <stdint.h>

typedef int v4i __attribute__((ext_vector_type(4)));

// ---------------- prep: quantize x (blocks 0..16383) + pack W (blocks 16384+) ----
__global__ __launch_bounds__(256) void prep_kernel(
    const float* __restrict__ x, int8_t* __restrict__ xq,
    const int* __restrict__ w, int8_t* __restrict__ w8,
    const float* __restrict__ s_p, const int* __restrict__ izp_p)
{
    const int b = blockIdx.x;
    if (b >= 16384) {                      // pack weight: int32 -> int8
        int t = (b - 16384) * 256 + threadIdx.x;   // 0..262143
        int4 v = ((const int4*)w)[t];
        ((int*)w8)[t] = (v.x & 255) | ((v.y & 255) << 8) |
                        ((v.z & 255) << 16) | ((v.w & 255) << 24);
        return;
    }
    int t = b * 256 + threadIdx.x;         // 16 elements per thread
    float s = *s_p;
    float zp = (float)(*izp_p);
    const float4* xin = (const float4*)x + (size_t)t * 4;
    int words[4];
#pragma unroll
    for (int i = 0; i < 4; ++i) {
        float4 v = xin[i];
        // round-half-even like jnp.round; exact IEEE division like the reference
        float q0 = fminf(127.f, fmaxf(-128.f, rintf(v.x / s) + zp));
        float q1 = fminf(127.f, fmaxf(-128.f, rintf(v.y / s) + zp));
        float q2 = fminf(127.f, fmaxf(-128.f, rintf(v.z / s) + zp));
        float q3 = fminf(127.f, fmaxf(-128.f, rintf(v.w / s) + zp));
        words[i] = ((int)q0 & 255) | (((int)q1 & 255) << 8) |
                   (((int)q2 & 255) << 16) | (((int)q3 & 255) << 24);
    }
    ((int4*)xq)[t] = make_int4(words[0], words[1], words[2], words[3]);
}

// ---------------- int8 GEMM: no-LDS register-direct ----------------
// Both operands are L2/L3-resident (A=64MB just written by prep; B=1MB), so
// LDS staging is pure overhead (guide Common-mistake #7). Each wave streams
// A/B fragments straight into VGPRs: no barriers, no LDS, no manual waitcnt.
// Full K-unroll -> all tile offsets fold to global-load imm offsets (t*64<4096).
#define GM 65536
#define GN 1024
#define GK 1024
#define NT 16   // K-tiles of 64

__global__ __launch_bounds__(256, 3) void gemm_i8_kernel(
    const int8_t* __restrict__ A,   // [GM][GK]
    const int8_t* __restrict__ B,   // [GN][GK]
    const int* __restrict__ bias,
    const float* __restrict__ osc_p, const int* __restrict__ ozp_p,
    float* __restrict__ out)
{
    const int tid = threadIdx.x;
    const int w = tid >> 6, l = tid & 63;
    const int wr = w >> 1, wc = w & 1;           // 2x2 wave grid, per-wave 64x64
    const int r15 = l & 15, s4 = l >> 4;

    // XCD-bijective: 8 consecutive logical blocks share one bm-panel (A panel
    // L2-resident on that XCD) and cover all 8 bn (B L2-resident everywhere).
    const int wg = blockIdx.x;
    const int lg = ((wg & 7) << 9) + (wg >> 3);
    const int bm0 = (lg >> 3) << 7;
    const int bn0 = (lg & 7) << 7;

    // 8 per-lane fragment stream bases; within a wave each stream covers
    // 16 rows x 64 B contiguous (lane group s4 spans the 64 B) -> L2-friendly.
    const int8_t* ap[4];
    const int8_t* bp[4];
#pragma unroll
    for (int i = 0; i < 4; ++i)
        ap[i] = A + (size_t)(bm0 + wr * 64 + i * 16 + r15) * GK + s4 * 16;
#pragma unroll
    for (int j = 0; j < 4; ++j)
        bp[j] = B + (size_t)(bn0 + wc * 64 + j * 16 + r15) * GK + s4 * 16;

    v4i acc[4][4];
#pragma unroll
    for (int i = 0; i < 4; ++i)
#pragma unroll
        for (int j = 0; j < 4; ++j) acc[i][j] = (v4i){0, 0, 0, 0};

    // Fully unrolled K loop: compiler software-pipelines the 8 loads of tile
    // t+1 above tile t's MFMA cluster within the VGPR budget (168 @ 3 w/EU).
#pragma unroll
    for (int t = 0; t < NT; ++t) {
        v4i af[4], bf[4];
#pragma unroll
        for (int i = 0; i < 4; ++i) af[i] = *(const v4i*)(ap[i] + t * 64);
#pragma unroll
        for (int j = 0; j < 4; ++j) bf[j] = *(const v4i*)(bp[j] + t * 64);
        __builtin_amdgcn_s_setprio(1);
#pragma unroll
        for (int i = 0; i < 4; ++i)
#pragma unroll
            for (int j = 0; j < 4; ++j)
                acc[i][j] = __builtin_amdgcn_mfma_i32_16x16x64_i8(af[i], bf[j], acc[i][j], 0, 0, 0);
        __builtin_amdgcn_s_setprio(0);
    }

    const float osc = *osc_p;
    const int ozp = *ozp_p;
    int bj[4];
#pragma unroll
    for (int j = 0; j < 4; ++j)
        bj[j] = bias[bn0 + wc * 64 + j * 16 + r15] - ozp;

    // C/D layout (16x16): col = l&15, row = (l>>4)*4 + reg  (r5 epilogue verbatim)
#pragma unroll
    for (int i = 0; i < 4; ++i) {
        const int mrow = bm0 + wr * 64 + i * 16 + s4 * 4;
#pragma unroll
        for (int j = 0; j < 4; ++j) {
            const int n = bn0 + wc * 64 + j * 16 + r15;
            float* op = out + (size_t)mrow * GN + n;
#pragma unroll
            for (int r = 0; r < 4; ++r)
                __builtin_nontemporal_store((float)(acc[i][j][r] + bj[j]) * osc,
                                            op + (size_t)r * GN);
        }
    }
}

extern "C" void kernel_launch(void* const* d_in, const int* in_sizes, int n_in,
                              void* d_out, int out_size, void* d_ws, size_t ws_size,
                              hipStream_t stream)
{
    const float* x         = (const float*)d_in[0];
    const int*   w_int     = (const int*)d_in[1];
    const int*   b_int     = (const int*)d_in[2];
    const float* in_scale  = (const float*)d_in[3];
    const float* out_scale = (const float*)d_in[4];
    const int*   izp       = (const int*)d_in[5];
    const int*   ozp       = (const int*)d_in[6];
    float* out = (float*)d_out;

    int8_t* xq = (int8_t*)d_ws;                            // 64 MB
    int8_t* w8 = (int8_t*)d_ws + (size_t)64 * 1024 * 1024; // 1 MB

    prep_kernel<<<16384 + 1024, 256, 0, stream>>>(x, xq, w_int, w8, in_scale, izp);
    gemm_i8_kernel<<<4096, 256, 0, stream>>>(xq, w8, b_int, out_scale, ozp, out);
}

// Round 13
// 158.319 us; speedup vs baseline: 1.8588x; 1.8588x over previous
//
#include <hip/hip_runtime.h>
#include <stdint.h>

typedef int v4i __attribute__((ext_vector_type(4)));

#define AS1(p) ((const __attribute__((address_space(1))) void*)(p))
#define AS3(p) ((__attribute__((address_space(3))) void*)(p))

// ---------------- prep: quantize x (blocks 0..16383) + pack W (blocks 16384+) ----
__global__ __launch_bounds__(256) void prep_kernel(
    const float* __restrict__ x, int8_t* __restrict__ xq,
    const int* __restrict__ w, int8_t* __restrict__ w8,
    const float* __restrict__ s_p, const int* __restrict__ izp_p)
{
    const int b = blockIdx.x;
    if (b >= 16384) {                      // pack weight: int32 -> int8
        int t = (b - 16384) * 256 + threadIdx.x;   // 0..262143
        int4 v = ((const int4*)w)[t];
        ((int*)w8)[t] = (v.x & 255) | ((v.y & 255) << 8) |
                        ((v.z & 255) << 16) | ((v.w & 255) << 24);
        return;
    }
    int t = b * 256 + threadIdx.x;         // 16 elements per thread
    float s = *s_p;
    float zp = (float)(*izp_p);
    const float4* xin = (const float4*)x + (size_t)t * 4;
    int words[4];
#pragma unroll
    for (int i = 0; i < 4; ++i) {
        float4 v = xin[i];
        // round-half-even like jnp.round; exact IEEE division like the reference
        float q0 = fminf(127.f, fmaxf(-128.f, rintf(v.x / s) + zp));
        float q1 = fminf(127.f, fmaxf(-128.f, rintf(v.y / s) + zp));
        float q2 = fminf(127.f, fmaxf(-128.f, rintf(v.z / s) + zp));
        float q3 = fminf(127.f, fmaxf(-128.f, rintf(v.w / s) + zp));
        words[i] = ((int)q0 & 255) | (((int)q1 & 255) << 8) |
                   (((int)q2 & 255) << 16) | (((int)q3 & 255) << 24);
    }
    ((int4*)xq)[t] = make_int4(words[0], words[1], words[2], words[3]);
}

// ---------------- int8 GEMM: 128x128 tile, 4 waves, 3-deep ring, counted vmcnt
#define GM 65536
#define GN 1024
#define GK 1024
#define NT 16   // K-tiles of 64

__global__ __launch_bounds__(256, 3) void gemm_i8_kernel(
    const int8_t* __restrict__ A,   // [GM][GK]
    const int8_t* __restrict__ B,   // [GN][GK]
    const int* __restrict__ bias,
    const float* __restrict__ osc_p, const int* __restrict__ ozp_p,
    float* __restrict__ out)
{
    // 3-deep ring: [buf][A/B][128 rows x 64 B], XOR slot-swizzle (slot ^= (row>>1)&3)
    __shared__ int8_t lds[3][2][8192];   // 48 KB -> 3 blocks/CU

    const int tid = threadIdx.x;
    const int w = tid >> 6, l = tid & 63;
    const int wr = w >> 1, wc = w & 1;           // 2x2 wave grid, per-wave 64x64
    const int r15 = l & 15, s4 = l >> 4;

    // XCD-bijective: grid 4096 = 8 XCD chunks x 512. Within a chunk, 8 consecutive
    // logical blocks share one bm-panel (A panel L2-resident) and cover all bn
    // (B is 1 MB -> L2-resident per XCD).
    const int wg = blockIdx.x;
    const int lg = ((wg & 7) << 9) + (wg >> 3);
    const int bm0 = (lg >> 3) << 7;
    const int bn0 = (lg & 7) << 7;

    // Staging: per thread 2 A + 2 B loads (16 B each) per K-tile. LDS dest linear
    // (wave-uniform base + lane*16); swizzle applied on the GLOBAL source col.
    const int8_t* a_src[2];
    const int8_t* b_src[2];
    int st_dst[2];
#pragma unroll
    for (int e = 0; e < 2; ++e) {
        int o = e * 4096 + tid * 16;             // linear LDS offset in 8 KB matrix buf
        int row = o >> 6;                        // 0..127
        int slot = (o >> 4) & 3;
        int gcol = ((slot ^ ((row >> 1) & 3)) << 4);
        a_src[e] = A + (size_t)(bm0 + row) * GK + gcol;
        b_src[e] = B + (size_t)(bn0 + row) * GK + gcol;
        st_dst[e] = e * 4096 + w * 1024;         // wave-uniform
    }

    // Fragment read offsets (same XOR on read)
    int a_off[4], b_off[4];
#pragma unroll
    for (int i = 0; i < 4; ++i) {
        int row = wr * 64 + i * 16 + r15;
        a_off[i] = (row << 6) + ((s4 ^ ((row >> 1) & 3)) << 4);
    }
#pragma unroll
    for (int j = 0; j < 4; ++j) {
        int row = wc * 64 + j * 16 + r15;
        b_off[j] = (row << 6) + ((s4 ^ ((row >> 1) & 3)) << 4);
    }

    v4i acc[4][4];
#pragma unroll
    for (int i = 0; i < 4; ++i)
#pragma unroll
        for (int j = 0; j < 4; ++j) acc[i][j] = (v4i){0, 0, 0, 0};

#define STAGE(T, BUF) do { \
    __builtin_amdgcn_global_load_lds(AS1(a_src[0] + (T) * 64), AS3(&lds[BUF][0][st_dst[0]]), 16, 0, 0); \
    __builtin_amdgcn_global_load_lds(AS1(a_src[1] + (T) * 64), AS3(&lds[BUF][0][st_dst[1]]), 16, 0, 0); \
    __builtin_amdgcn_global_load_lds(AS1(b_src[0] + (T) * 64), AS3(&lds[BUF][1][st_dst[0]]), 16, 0, 0); \
    __builtin_amdgcn_global_load_lds(AS1(b_src[1] + (T) * 64), AS3(&lds[BUF][1][st_dst[1]]), 16, 0, 0); \
} while (0)

// No setprio: T5 is ~0-to-negative on lockstep (non-phase-split) GEMM (m190).
#define COMPUTE(BUF) do { \
    v4i af[4], bf[4]; \
    _Pragma("unroll") \
    for (int j = 0; j < 4; ++j) bf[j] = *(const v4i*)&lds[BUF][1][b_off[j]]; \
    _Pragma("unroll") \
    for (int i = 0; i < 4; ++i) af[i] = *(const v4i*)&lds[BUF][0][a_off[i]]; \
    _Pragma("unroll") \
    for (int i = 0; i < 4; ++i) \
    _Pragma("unroll") \
        for (int j = 0; j < 4; ++j) \
            acc[i][j] = __builtin_amdgcn_mfma_i32_16x16x64_i8(af[i], bf[j], acc[i][j], 0, 0, 0); \
} while (0)

    // Prologue: prefetch tiles 0,1 (8 loads/wave in flight)
    STAGE(0, 0);
    STAGE(1, 1);

    // Iter t: vmcnt(4) = tile t landed (t+1 in flight); barrier also guarantees
    // no wave still reads buf (t+2)%3 (its tile t-1 reads finished before the
    // PREVIOUS barrier). Stage t+2, compute t. Never drain to 0 mid-loop.
    int c0 = 0, c1 = 1, c2 = 2;
#pragma unroll 1
    for (int t = 0; t < NT - 2; ++t) {
        asm volatile("s_waitcnt vmcnt(4)" ::: "memory");
        __builtin_amdgcn_s_barrier();
        STAGE(t + 2, c2);
        COMPUTE(c0);
        int tmp = c0; c0 = c1; c1 = c2; c2 = tmp;   // rotate ring
    }
    // Tail: tiles 14,15
    asm volatile("s_waitcnt vmcnt(4)" ::: "memory");
    __builtin_amdgcn_s_barrier();
    COMPUTE(c0);
    asm volatile("s_waitcnt vmcnt(0)" ::: "memory");
    __builtin_amdgcn_s_barrier();
    COMPUTE(c1);

#undef STAGE
#undef COMPUTE

    const float osc = *osc_p;
    const int ozp = *ozp_p;
    int bj[4];
#pragma unroll
    for (int j = 0; j < 4; ++j)
        bj[j] = bias[bn0 + wc * 64 + j * 16 + r15] - ozp;

    // C/D layout (16x16): col = l&15, row = (l>>4)*4 + reg
#pragma unroll
    for (int i = 0; i < 4; ++i) {
        const int mrow = bm0 + wr * 64 + i * 16 + s4 * 4;
#pragma unroll
        for (int j = 0; j < 4; ++j) {
            const int n = bn0 + wc * 64 + j * 16 + r15;
            float* op = out + (size_t)mrow * GN + n;
#pragma unroll
            for (int r = 0; r < 4; ++r)
                __builtin_nontemporal_store((float)(acc[i][j][r] + bj[j]) * osc,
                                            op + (size_t)r * GN);
        }
    }
}

extern "C" void kernel_launch(void* const* d_in, const int* in_sizes, int n_in,
                              void* d_out, int out_size, void* d_ws, size_t ws_size,
                              hipStream_t stream)
{
    const float* x         = (const float*)d_in[0];
    const int*   w_int     = (const int*)d_in[1];
    const int*   b_int     = (const int*)d_in[2];
    const float* in_scale  = (const float*)d_in[3];
    const float* out_scale = (const float*)d_in[4];
    const int*   izp       = (const int*)d_in[5];
    const int*   ozp       = (const int*)d_in[6];
    float* out = (float*)d_out;

    int8_t* xq = (int8_t*)d_ws;                            // 64 MB
    int8_t* w8 = (int8_t*)d_ws + (size_t)64 * 1024 * 1024; // 1 MB

    prep_kernel<<<16384 + 1024, 256, 0, stream>>>(x, xq, w_int, w8, in_scale, izp);
    gemm_i8_kernel<<<4096, 256, 0, stream>>>(xq, w8, b_int, out_scale, ozp, out);
}